// Round 13
// baseline (180.027 us; speedup 1.0000x reference)
//
#include <hip/hip_runtime.h>

// SelfAttention (SAGAN-style) on MI355X.
// B=2, C=64, C8=8, H=W=96, N=9216.  out = gamma * Attn(g,f,h) + x
//   K = f = (Wq/sq) x + bq   (pre-scaled by log2e; softmax in exp2 domain)
//   Q = g = (Wk/sk) x + bk
//   V = h = (Wv/sv) x + bv
// softmax over keys i; head_dim 8 (zero-padded), dv=64.
//
// R13: software-pipelined k_attn round body. R12 evidence: no pipe >45%
// busy at 70us -> ~half is exposed serial chain (dsK->S->exp2->shfl->PV
// ~440cyc/round). Now PV(r-1) runs on registers held from the previous
// round, issued right after S(r) (fills S latency); all 5 DS reads (K+4V)
// bundled in ONE pinned asm with a single lgkmcnt(0); P/V rotate through
// two named register sets (unroll-2, SROA-proof); round -1 P/V zeroed.
// Staging/swizzle/numerics/k_sigma/k_fgh/k_merge unchanged from R12.

#define N_PIX 9216
#define N_B   2
#define N_C   64

typedef _Float16 half8  __attribute__((ext_vector_type(8)));
typedef float    float4v __attribute__((ext_vector_type(4)));
typedef float    float16v __attribute__((ext_vector_type(16)));
typedef int      int4v  __attribute__((ext_vector_type(4)));

#define LOG2E 1.44269504088896340736f
#define EXP_SHIFT 12.0f

// ---------------------------------------------------------------- k_sigma
__global__ __launch_bounds__(64) void k_sigma(const float* __restrict__ Wq,
                                              const float* __restrict__ Wk,
                                              const float* __restrict__ Wv,
                                              float* __restrict__ sig,
                                              unsigned* __restrict__ maxKu) {
  __shared__ float G8[8][8];
  __shared__ float Wl[64 * 64];
  __shared__ _Float16 Wh[64 * 80];
  __shared__ _Float16 Gh[64 * 80];
  const int t = threadIdx.x;
  const int mat = blockIdx.x;
  if (mat == 0 && t < 2) maxKu[t] = 0u;
  if (mat < 2) {
    const float* W = (mat == 0) ? Wq : Wk;
    const int i = t >> 3, j = t & 7;
    float g = 0.f;
    for (int c = 0; c < 64; ++c) g += W[i * 64 + c] * W[j * 64 + c];
    G8[i][j] = g;
    __syncthreads();
    const int L = t & 7;
    float G0[8], Gr[8];
    for (int k = 0; k < 8; ++k) { G0[k] = G8[L][k]; Gr[k] = G0[k]; }
    for (int it = 0; it < 8; ++it) {
      float g2[8] = {0, 0, 0, 0, 0, 0, 0, 0};
      for (int k = 0; k < 8; ++k) {
        float gik = Gr[k];
        for (int jj = 0; jj < 8; ++jj) g2[jj] += gik * __shfl(Gr[jj], k, 64);
      }
      float mx = 0.f;
      for (int jj = 0; jj < 8; ++jj) mx = fmaxf(mx, fabsf(g2[jj]));
      for (int d = 1; d < 8; d <<= 1) mx = fmaxf(mx, __shfl_xor(mx, d, 64));
      float r = 1.f / mx;
      for (int jj = 0; jj < 8; ++jj) Gr[jj] = g2[jj] * r;
    }
    float u = 0.f;
    for (int jj = 0; jj < 8; ++jj) u += Gr[jj];
    float y = 0.f;
    for (int k = 0; k < 8; ++k) y += G0[k] * __shfl(u, k, 64);
    float nu = u * y, de = u * u;
    for (int d = 1; d < 8; d <<= 1) { nu += __shfl_xor(nu, d, 64); de += __shfl_xor(de, d, 64); }
    if (t == 0) sig[mat] = sqrtf(nu / de);
  } else {
    for (int idx = t; idx < 4096; idx += 64) Wl[idx] = Wv[idx];
    __syncthreads();
    for (int idx = t; idx < 4096; idx += 64) Wh[(idx >> 6) * 80 + (idx & 63)] = (_Float16)Wl[idx];
    __syncthreads();
    const int lane15 = t & 15, quad = t >> 4;
    half8 fr[4][2];
    for (int rb = 0; rb < 4; ++rb)
      for (int kc = 0; kc < 2; ++kc)
        fr[rb][kc] = *(const half8*)&Wh[(lane15 + 16 * rb) * 80 + 32 * kc + 8 * quad];
    float4v D[4][4];
    for (int mb = 0; mb < 4; ++mb) for (int nb = 0; nb < 4; ++nb) D[mb][nb] = (float4v){0.f, 0.f, 0.f, 0.f};
    for (int kc = 0; kc < 2; ++kc)
      for (int mb = 0; mb < 4; ++mb)
        for (int nb = 0; nb < 4; ++nb)
          D[mb][nb] = __builtin_amdgcn_mfma_f32_16x16x32_f16(fr[mb][kc], fr[nb][kc], D[mb][nb], 0, 0, 0);
    for (int it = 0; it < 8; ++it) {
      float mx = 0.f;
      for (int mb = 0; mb < 4; ++mb) for (int nb = 0; nb < 4; ++nb) for (int r = 0; r < 4; ++r)
        mx = fmaxf(mx, fabsf(D[mb][nb][r]));
      for (int d = 1; d < 64; d <<= 1) mx = fmaxf(mx, __shfl_xor(mx, d, 64));
      float rs = 1.f / mx;
      for (int mb = 0; mb < 4; ++mb) for (int nb = 0; nb < 4; ++nb) for (int r = 0; r < 4; ++r)
        Gh[(4 * quad + r + 16 * mb) * 80 + lane15 + 16 * nb] = (_Float16)(D[mb][nb][r] * rs);
      __syncthreads();
      if (it == 7) break;
      for (int rb = 0; rb < 4; ++rb)
        for (int kc = 0; kc < 2; ++kc)
          fr[rb][kc] = *(const half8*)&Gh[(lane15 + 16 * rb) * 80 + 32 * kc + 8 * quad];
      for (int mb = 0; mb < 4; ++mb) for (int nb = 0; nb < 4; ++nb) D[mb][nb] = (float4v){0.f, 0.f, 0.f, 0.f};
      for (int kc = 0; kc < 2; ++kc)
        for (int mb = 0; mb < 4; ++mb)
          for (int nb = 0; nb < 4; ++nb)
            D[mb][nb] = __builtin_amdgcn_mfma_f32_16x16x32_f16(fr[mb][kc], fr[nb][kc], D[mb][nb], 0, 0, 0);
      __syncthreads();
    }
    float u = 0.f;
    for (int c = 0; c < 64; ++c) u += (float)Gh[t * 80 + c];
    float z = 0.f;
    for (int i2 = 0; i2 < 64; ++i2) z += Wl[i2 * 64 + t] * __shfl(u, i2, 64);
    float nu = z * z, de = u * u;
    for (int d = 1; d < 64; d <<= 1) { nu += __shfl_xor(nu, d, 64); de += __shfl_xor(de, d, 64); }
    if (t == 0) sig[2] = sqrtf(nu / de);
  }
}

// ---------------------------------------------------------------- k_fgh
__global__ __launch_bounds__(256) void k_fgh(const float* __restrict__ x,
                                             const float* __restrict__ Wq, const float* __restrict__ bq,
                                             const float* __restrict__ Wk, const float* __restrict__ bk,
                                             const float* __restrict__ Wv, const float* __restrict__ bv,
                                             const float* __restrict__ sig,
                                             _Float16* __restrict__ K16,
                                             _Float16* __restrict__ Q16,
                                             _Float16* __restrict__ VT16,
                                             unsigned* __restrict__ maxKu) {
  __shared__ _Float16 Wsh[80 * 64];
  __shared__ float bsh[80];
  const int t = threadIdx.x;
  const float iq = LOG2E / sig[0], ik = 1.0f / sig[1], iv = 1.0f / sig[2];
  for (int idx = t; idx < 80 * 64; idx += 256) {
    const int m = idx >> 6, c = idx & 63;
    float v;
    if (m < 8)       v = Wq[m * 64 + c] * iq;
    else if (m < 16) v = Wk[(m - 8) * 64 + c] * ik;
    else             v = Wv[(m - 16) * 64 + c] * iv;
    Wsh[idx] = (_Float16)v;
  }
  if (t < 80) {
    float v;
    if (t < 8)       v = bq[t] * LOG2E;
    else if (t < 16) v = bk[t - 8];
    else             v = bv[t - 16];
    bsh[t] = v;
  }
  __syncthreads();
  const int wave = t >> 6;
  const int lane = t & 63;
  const int lane15 = lane & 15, quad = lane >> 4;
  const int tile = blockIdx.x * 4 + wave;
  const int b = tile / 576;
  const int n = (tile % 576) * 16 + lane15;
  half8 wf[5][2];
  for (int mb = 0; mb < 5; ++mb)
    for (int kc = 0; kc < 2; ++kc)
      wf[mb][kc] = *(const half8*)&Wsh[(lane15 + 16 * mb) * 64 + 32 * kc + 8 * quad];
  float4v acc[5];
  for (int mb = 0; mb < 5; ++mb) acc[mb] = *(const float4v*)&bsh[16 * mb + 4 * quad];
  const float* xb = x + (size_t)b * N_C * N_PIX;
  for (int kc = 0; kc < 2; ++kc) {
    half8 bf;
    for (int j = 0; j < 8; ++j)
      bf[j] = (_Float16)xb[(size_t)(32 * kc + 8 * quad + j) * N_PIX + n];
    for (int mb = 0; mb < 5; ++mb)
      acc[mb] = __builtin_amdgcn_mfma_f32_16x16x32_f16(wf[mb][kc], bf, acc[mb], 0, 0, 0);
  }
  {
    _Float16* dstK = K16 + ((size_t)b * N_PIX + n) * 8;
    _Float16* dstQ = Q16 + ((size_t)b * N_PIX + n) * 8;
    for (int r = 0; r < 4; ++r) {
      const int m = 4 * quad + r;
      const _Float16 v = (_Float16)acc[0][r];
      if (m < 8) dstK[m] = v; else dstQ[m - 8] = v;
    }
  }
  for (int mb = 1; mb < 5; ++mb)
    for (int r = 0; r < 4; ++r) {
      const int c = 4 * quad + r + 16 * (mb - 1);
      VT16[((size_t)b * N_C + c) * N_PIX + n] = (_Float16)acc[mb][r];
    }
  float sq = 0.f;
  if (quad < 2)
    for (int r = 0; r < 4; ++r) sq += acc[0][r] * acc[0][r];
  sq += __shfl_xor(sq, 16, 64);
  for (int d = 1; d < 64; d <<= 1) sq = fmaxf(sq, __shfl_xor(sq, d, 64));
  if (lane == 0) atomicMax(&maxKu[b], __float_as_uint(sq));
}

// ---------------------------------------------------------------- k_attn
// 1152 blocks (2-way key split), 4 waves, 36 rounds of 32 keys/wave.
// Software-pipelined: PV(r-1) from registers; DS5 = K+4V reads in one
// pinned asm with single lgkmcnt(0). Partial O/l to workspace.

__device__ __forceinline__ void gload16(const _Float16* g, _Float16* l) {
  __builtin_amdgcn_global_load_lds(
      (const __attribute__((address_space(1))) void*)g,
      (__attribute__((address_space(3))) void*)l, 16, 0, 0);
}
#define VMWAIT5() asm volatile("s_waitcnt vmcnt(5)" ::: "memory")
typedef const __attribute__((address_space(3))) _Float16* lds_cp;
#define DS5(K, V0, V1, V2, V3, PK, PV0, PV1, PV2, PV3)                   \
  asm volatile("ds_read_b128 %0, %5\n\t"                                 \
               "ds_read_b128 %1, %6\n\t"                                 \
               "ds_read_b128 %2, %7\n\t"                                 \
               "ds_read_b128 %3, %8\n\t"                                 \
               "ds_read_b128 %4, %9\n\t"                                 \
               "s_waitcnt lgkmcnt(0)"                                    \
               : "=&v"(K), "=&v"(V0), "=&v"(V1), "=&v"(V2), "=&v"(V3)    \
               : "v"(PK), "v"(PV0), "v"(PV1), "v"(PV2), "v"(PV3) : "memory")

__global__ __launch_bounds__(256, 4) void k_attn(const _Float16* __restrict__ K16,
                                                 const _Float16* __restrict__ Q16,
                                                 const _Float16* __restrict__ VT16,
                                                 const unsigned* __restrict__ maxKu,
                                                 float* __restrict__ Opart,
                                                 float* __restrict__ Lpart) {
  __shared__ __align__(16) _Float16 SM[4][5120];   // 40960 B -> 4 blocks/CU
  const int wave = threadIdx.x >> 6;
  const int lane = threadIdx.x & 63;
  const int q31 = lane & 31, hi = lane >> 5;
  const int tile = blockIdx.x;            // 0..1151
  const int b = tile / 576;
  const int rm = tile % 576;
  const int jb = (rm >> 1) * 32;
  const int h = rm & 1;
  const int kh = h * (N_PIX / 2);
  const _Float16* Kb = K16 + (size_t)b * N_PIX * 8;
  const _Float16* Vb = VT16 + (size_t)b * N_C * N_PIX;
  _Float16* Rg = SM[wave];
  const int cl = lane >> 2, kk = lane & 3;
  const int gsw = (kk ^ ((cl >> 1) & 3)) * 8;
  const int vx = (q31 >> 1) & 3;
  const int voff00 = q31 * 32 + ((hi ^ vx) << 3);
  const int voff01 = q31 * 32 + (((2 + hi) ^ vx) << 3);
  const int voff10 = 1024 + voff00;
  const int voff11 = 1024 + voff01;

  half8 qf = {};
  if (hi == 0) qf = *(const half8*)(Q16 + ((size_t)b * N_PIX + jb + q31) * 8);
  const float maxK = sqrtf(__uint_as_float(maxKu[b]));
  float nq = 0.f;
#pragma unroll
  for (int j = 0; j < 8; ++j) nq += (float)qf[j] * (float)qf[j];
  nq += __shfl_xor(nq, 32, 64);
  const float M = sqrtf(nq) * maxK - EXP_SHIFT;
  float16v sinit;
#pragma unroll
  for (int r2 = 0; r2 < 16; ++r2) sinit[r2] = -M;

  float16v acc0 = {}, acc1 = {};
  float ls = 0.f;

#define STAGE(SLOT, I0)                                                          \
  {                                                                              \
    const int _i = (I0);                                                         \
    gload16(Kb + (size_t)(_i + q31) * 8, Rg + 4096 + (SLOT) * 512);              \
    gload16(Vb + (size_t)cl * N_PIX + _i + gsw,        Rg + (SLOT) * 2048);      \
    gload16(Vb + (size_t)(16 + cl) * N_PIX + _i + gsw, Rg + (SLOT) * 2048 + 512);\
    gload16(Vb + (size_t)(32 + cl) * N_PIX + _i + gsw, Rg + (SLOT) * 2048 + 1024);\
    gload16(Vb + (size_t)(48 + cl) * N_PIX + _i + gsw, Rg + (SLOT) * 2048 + 1536);\
  }

  // rotating register sets (named -> SROA-proof). Round -1 = zeros.
  int4v Pa0 = {}, Pa1 = {}, Va0 = {}, Va1 = {}, Va2 = {}, Va3 = {};
  int4v Pb0, Pb1, Vb0, Vb1, Vb2, Vb3;

#define BODY(R, SLOT, NSLOT, PP0, PP1, VP0, VP1, VP2, VP3, PC0, PC1, VC0, VC1, VC2, VC3) \
  {                                                                                      \
    const int i1 = kh + (((R) < 35) ? (128 * ((R) + 1) + 32 * wave)                      \
                                    : (128 * 35 + 32 * wave));                           \
    STAGE(NSLOT, i1)                                                                     \
    VMWAIT5();                                                                           \
    int4v kfi;                                                                           \
    {                                                                                    \
      lds_cp pk  = (lds_cp)(Rg + 4096 + (SLOT) * 512 + q31 * 8);                         \
      lds_cp pv0 = (lds_cp)(Rg + (SLOT) * 2048 + voff00);                                \
      lds_cp pv1 = (lds_cp)(Rg + (SLOT) * 2048 + voff01);                                \
      lds_cp pv2 = (lds_cp)(Rg + (SLOT) * 2048 + voff10);                                \
      lds_cp pv3 = (lds_cp)(Rg + (SLOT) * 2048 + voff11);                                \
      DS5(kfi, VC0, VC1, VC2, VC3, pk, pv0, pv1, pv2, pv3);                              \
    }                                                                                    \
    half8 kf = __builtin_bit_cast(half8, kfi);                                           \
    if (hi) kf = (half8){};                                                              \
    float16v s = __builtin_amdgcn_mfma_f32_32x32x16_f16(kf, qf, sinit, 0, 0, 0);         \
    /* PV(prev) on held registers: fills S latency */                                    \
    acc0 = __builtin_amdgcn_mfma_f32_32x32x16_f16(__builtin_bit_cast(half8, VP0),        \
                                                  __builtin_bit_cast(half8, PP0), acc0, 0, 0, 0); \
    acc0 = __builtin_amdgcn_mfma_f32_32x32x16_f16(__builtin_bit_cast(half8, VP1),        \
                                                  __builtin_bit_cast(half8, PP1), acc0, 0, 0, 0); \
    acc1 = __builtin_amdgcn_mfma_f32_32x32x16_f16(__builtin_bit_cast(half8, VP2),        \
                                                  __builtin_bit_cast(half8, PP0), acc1, 0, 0, 0); \
    acc1 = __builtin_amdgcn_mfma_f32_32x32x16_f16(__builtin_bit_cast(half8, VP3),        \
                                                  __builtin_bit_cast(half8, PP1), acc1, 0, 0, 0); \
    /* p = exp2(s); pack; lane<->lane^32 exchange -> P(cur) */                           \
    int pkv[8];                                                                          \
    _Pragma("unroll") for (int u = 0; u < 8; ++u) {                                      \
      const float p0 = __builtin_amdgcn_exp2f(s[2 * u]);                                 \
      const float p1 = __builtin_amdgcn_exp2f(s[2 * u + 1]);                             \
      ls += p0 + p1;                                                                     \
      pkv[u] = __builtin_bit_cast(int, __builtin_amdgcn_cvt_pkrtz(p0, p1));              \
    }                                                                                    \
    const int t0 = hi ? pkv[0] : pkv[2];                                                 \
    const int t1 = hi ? pkv[1] : pkv[3];                                                 \
    const int t2 = hi ? pkv[4] : pkv[6];                                                 \
    const int t3 = hi ? pkv[5] : pkv[7];                                                 \
    const int x0 = __shfl_xor(t0, 32, 64);                                               \
    const int x1 = __shfl_xor(t1, 32, 64);                                               \
    const int x2 = __shfl_xor(t2, 32, 64);                                               \
    const int x3 = __shfl_xor(t3, 32, 64);                                               \
    PC0[0] = hi ? x0 : pkv[0];  PC0[1] = hi ? x1 : pkv[1];                               \
    PC0[2] = hi ? pkv[2] : x0;  PC0[3] = hi ? pkv[3] : x1;                               \
    PC1[0] = hi ? x2 : pkv[4];  PC1[1] = hi ? x3 : pkv[5];                               \
    PC1[2] = hi ? pkv[6] : x2;  PC1[3] = hi ? pkv[7] : x3;                               \
  }

  STAGE(0, kh + 32 * wave)
#pragma unroll 1
  for (int j2 = 0; j2 < 18; ++j2) {
    const int r = 2 * j2;
    BODY(r,     0, 1, Pa0, Pa1, Va0, Va1, Va2, Va3, Pb0, Pb1, Vb0, Vb1, Vb2, Vb3)
    BODY(r + 1, 1, 0, Pb0, Pb1, Vb0, Vb1, Vb2, Vb3, Pa0, Pa1, Va0, Va1, Va2, Va3)
  }
#undef BODY
#undef STAGE
  asm volatile("s_waitcnt vmcnt(0)" ::: "memory");  // drain dangling staging
  // tail: PV(35) (producer was the last BODY -> Pa/Va set)
  acc0 = __builtin_amdgcn_mfma_f32_32x32x16_f16(__builtin_bit_cast(half8, Va0),
                                                __builtin_bit_cast(half8, Pa0), acc0, 0, 0, 0);
  acc0 = __builtin_amdgcn_mfma_f32_32x32x16_f16(__builtin_bit_cast(half8, Va1),
                                                __builtin_bit_cast(half8, Pa1), acc0, 0, 0, 0);
  acc1 = __builtin_amdgcn_mfma_f32_32x32x16_f16(__builtin_bit_cast(half8, Va2),
                                                __builtin_bit_cast(half8, Pa0), acc1, 0, 0, 0);
  acc1 = __builtin_amdgcn_mfma_f32_32x32x16_f16(__builtin_bit_cast(half8, Va3),
                                                __builtin_bit_cast(half8, Pa1), acc1, 0, 0, 0);

  // ---- cross-wave merge in own region, then write partials (undivided).
  float* Ow = (float*)Rg;                // 64 x 17 f32
  float* Lw = (float*)Rg + 1100;         // 32 f32
  ls += __shfl_xor(ls, 32, 64);
  if (hi == 0) Lw[q31] = ls;
#pragma unroll
  for (int r2 = 0; r2 < 16; ++r2) Ow[lane * 17 + r2] = acc0[r2];
  __syncthreads();
  float ltot = 0.f;
#pragma unroll
  for (int w = 0; w < 4; ++w) ltot += ((const float*)SM[w])[1100 + q31];
  float* Op = Opart + (size_t)tile * 2048;
  if (wave == 0 && hi == 0) Lpart[tile * 32 + q31] = ltot;
#pragma unroll
  for (int r2 = 0; r2 < 16; ++r2) {
    float osum = 0.f;
#pragma unroll
    for (int w = 0; w < 4; ++w) osum += ((const float*)SM[w])[lane * 17 + r2];
    const int c = (r2 & 3) + 8 * (r2 >> 2) + 4 * hi;
    Op[c * 32 + q31] = osum;
  }
  __syncthreads();
#pragma unroll
  for (int r2 = 0; r2 < 16; ++r2) Ow[lane * 17 + r2] = acc1[r2];
  __syncthreads();
#pragma unroll
  for (int r2 = 0; r2 < 16; ++r2) {
    float osum = 0.f;
#pragma unroll
    for (int w = 0; w < 4; ++w) osum += ((const float*)SM[w])[lane * 17 + r2];
    const int c = 32 + (r2 & 3) + 8 * (r2 >> 2) + 4 * hi;
    Op[c * 32 + q31] = osum;
  }
}

// ---------------------------------------------------------------- k_merge
__global__ __launch_bounds__(256) void k_merge(const float* __restrict__ Opart,
                                               const float* __restrict__ Lpart,
                                               const float* __restrict__ x,
                                               const float* __restrict__ gamma,
                                               float* __restrict__ out) {
  __shared__ float Ls[32];
  const int t2 = blockIdx.x;              // 0..575
  const int b = t2 / 288, jt = t2 % 288;
  const int jb = jt * 32;
  const int tile0 = b * 576 + jt * 2;
  const float gm = gamma[0];
  const int t = threadIdx.x;
  if (t < 32) Ls[t] = Lpart[tile0 * 32 + t] + Lpart[(tile0 + 1) * 32 + t];
  __syncthreads();
  const float* O0 = Opart + (size_t)tile0 * 2048;
  const float* O1 = O0 + 2048;
  const float* xb = x + (size_t)b * N_C * N_PIX;
  float* ob = out + (size_t)b * N_C * N_PIX;
#pragma unroll
  for (int k = 0; k < 8; ++k) {
    const int idx = t + 256 * k;
    const int c = idx >> 5, q = idx & 31;
    const size_t gi = (size_t)c * N_PIX + jb + q;
    ob[gi] = gm * (O0[idx] + O1[idx]) / Ls[q] + xb[gi];
  }
}

// ---------------------------------------------------------------- launch
extern "C" void kernel_launch(void* const* d_in, const int* in_sizes, int n_in,
                              void* d_out, int out_size, void* d_ws, size_t ws_size,
                              hipStream_t stream) {
  const float* x     = (const float*)d_in[0];
  const float* Wq    = (const float*)d_in[1];
  const float* bq    = (const float*)d_in[2];
  const float* Wk    = (const float*)d_in[3];
  const float* bk    = (const float*)d_in[4];
  const float* Wv    = (const float*)d_in[5];
  const float* bv    = (const float*)d_in[6];
  const float* gamma = (const float*)d_in[7];
  float* out = (float*)d_out;

  char* ws = (char*)d_ws;
  float*    sig   = (float*)ws;                       // 4 floats
  unsigned* maxKu = (unsigned*)(ws + 16);             // 2 uints
  _Float16* K16   = (_Float16*)(ws + 10752);          // 294912 B
  _Float16* Q16   = (_Float16*)(ws + 10752 + 294912); // 294912 B
  _Float16* VT16  = (_Float16*)(ws + 10752 + 2 * 294912); // 2359296 B
  float*    Opart = (float*)(ws + 2960384);           // 9437184 B
  float*    Lpart = (float*)(ws + 2960384 + 9437184); // 147456 B

  hipLaunchKernelGGL(k_sigma, dim3(3), dim3(64), 0, stream, Wq, Wk, Wv, sig, maxKu);
  hipLaunchKernelGGL(k_fgh, dim3(288), dim3(256), 0, stream,
                     x, Wq, bq, Wk, bk, Wv, bv, sig, K16, Q16, VT16, maxKu);
  hipLaunchKernelGGL(k_attn, dim3(1152), dim3(256), 0, stream, K16, Q16, VT16, maxKu, Opart, Lpart);
  hipLaunchKernelGGL(k_merge, dim3(576), dim3(256), 0, stream, Opart, Lpart, x, gamma, out);
}

// Round 14
// 172.106 us; speedup vs baseline: 1.0460x; 1.0460x over previous
//
#include <hip/hip_runtime.h>

// SelfAttention (SAGAN-style) on MI355X.
// B=2, C=64, C8=8, H=W=96, N=9216.  out = gamma * Attn(g,f,h) + x
//   K = f = (Wq/sq) x + bq   (pre-scaled by log2e; softmax in exp2 domain)
//   Q = g = (Wk/sk) x + bk
//   V = h = (Wv/sv) x + bv
// softmax over keys i; head_dim 8 (zero-padded), dv=64.
//
// R14: REVERT k_attn to R12 (best known, 69.9us). R13's software pipeline
// (+48 VGPRs of rotating P/V buffers) spilled: WRITE_SIZE 9.4->19MB at
// VGPR_Count=64. Rule learned (4th occurrence): only MFMA accumulators
// survive as loop-carried registers on this compiler; everything else gets
// spilled or sunk. k_merge gains float4 vectorization (minor).
// Numerics unchanged (M = |Q|*max|K'| - 12, f16 P, f32 lsum).

#define N_PIX 9216
#define N_B   2
#define N_C   64

typedef _Float16 half8  __attribute__((ext_vector_type(8)));
typedef float    float4v __attribute__((ext_vector_type(4)));
typedef float    float16v __attribute__((ext_vector_type(16)));
typedef int      int4v  __attribute__((ext_vector_type(4)));

#define LOG2E 1.44269504088896340736f
#define EXP_SHIFT 12.0f

// ---------------------------------------------------------------- k_sigma
__global__ __launch_bounds__(64) void k_sigma(const float* __restrict__ Wq,
                                              const float* __restrict__ Wk,
                                              const float* __restrict__ Wv,
                                              float* __restrict__ sig,
                                              unsigned* __restrict__ maxKu) {
  __shared__ float G8[8][8];
  __shared__ float Wl[64 * 64];
  __shared__ _Float16 Wh[64 * 80];
  __shared__ _Float16 Gh[64 * 80];
  const int t = threadIdx.x;
  const int mat = blockIdx.x;
  if (mat == 0 && t < 2) maxKu[t] = 0u;
  if (mat < 2) {
    const float* W = (mat == 0) ? Wq : Wk;
    const int i = t >> 3, j = t & 7;
    float g = 0.f;
    for (int c = 0; c < 64; ++c) g += W[i * 64 + c] * W[j * 64 + c];
    G8[i][j] = g;
    __syncthreads();
    const int L = t & 7;
    float G0[8], Gr[8];
    for (int k = 0; k < 8; ++k) { G0[k] = G8[L][k]; Gr[k] = G0[k]; }
    for (int it = 0; it < 8; ++it) {
      float g2[8] = {0, 0, 0, 0, 0, 0, 0, 0};
      for (int k = 0; k < 8; ++k) {
        float gik = Gr[k];
        for (int jj = 0; jj < 8; ++jj) g2[jj] += gik * __shfl(Gr[jj], k, 64);
      }
      float mx = 0.f;
      for (int jj = 0; jj < 8; ++jj) mx = fmaxf(mx, fabsf(g2[jj]));
      for (int d = 1; d < 8; d <<= 1) mx = fmaxf(mx, __shfl_xor(mx, d, 64));
      float r = 1.f / mx;
      for (int jj = 0; jj < 8; ++jj) Gr[jj] = g2[jj] * r;
    }
    float u = 0.f;
    for (int jj = 0; jj < 8; ++jj) u += Gr[jj];
    float y = 0.f;
    for (int k = 0; k < 8; ++k) y += G0[k] * __shfl(u, k, 64);
    float nu = u * y, de = u * u;
    for (int d = 1; d < 8; d <<= 1) { nu += __shfl_xor(nu, d, 64); de += __shfl_xor(de, d, 64); }
    if (t == 0) sig[mat] = sqrtf(nu / de);
  } else {
    for (int idx = t; idx < 4096; idx += 64) Wl[idx] = Wv[idx];
    __syncthreads();
    for (int idx = t; idx < 4096; idx += 64) Wh[(idx >> 6) * 80 + (idx & 63)] = (_Float16)Wl[idx];
    __syncthreads();
    const int lane15 = t & 15, quad = t >> 4;
    half8 fr[4][2];
    for (int rb = 0; rb < 4; ++rb)
      for (int kc = 0; kc < 2; ++kc)
        fr[rb][kc] = *(const half8*)&Wh[(lane15 + 16 * rb) * 80 + 32 * kc + 8 * quad];
    float4v D[4][4];
    for (int mb = 0; mb < 4; ++mb) for (int nb = 0; nb < 4; ++nb) D[mb][nb] = (float4v){0.f, 0.f, 0.f, 0.f};
    for (int kc = 0; kc < 2; ++kc)
      for (int mb = 0; mb < 4; ++mb)
        for (int nb = 0; nb < 4; ++nb)
          D[mb][nb] = __builtin_amdgcn_mfma_f32_16x16x32_f16(fr[mb][kc], fr[nb][kc], D[mb][nb], 0, 0, 0);
    for (int it = 0; it < 8; ++it) {
      float mx = 0.f;
      for (int mb = 0; mb < 4; ++mb) for (int nb = 0; nb < 4; ++nb) for (int r = 0; r < 4; ++r)
        mx = fmaxf(mx, fabsf(D[mb][nb][r]));
      for (int d = 1; d < 64; d <<= 1) mx = fmaxf(mx, __shfl_xor(mx, d, 64));
      float rs = 1.f / mx;
      for (int mb = 0; mb < 4; ++mb) for (int nb = 0; nb < 4; ++nb) for (int r = 0; r < 4; ++r)
        Gh[(4 * quad + r + 16 * mb) * 80 + lane15 + 16 * nb] = (_Float16)(D[mb][nb][r] * rs);
      __syncthreads();
      if (it == 7) break;
      for (int rb = 0; rb < 4; ++rb)
        for (int kc = 0; kc < 2; ++kc)
          fr[rb][kc] = *(const half8*)&Gh[(lane15 + 16 * rb) * 80 + 32 * kc + 8 * quad];
      for (int mb = 0; mb < 4; ++mb) for (int nb = 0; nb < 4; ++nb) D[mb][nb] = (float4v){0.f, 0.f, 0.f, 0.f};
      for (int kc = 0; kc < 2; ++kc)
        for (int mb = 0; mb < 4; ++mb)
          for (int nb = 0; nb < 4; ++nb)
            D[mb][nb] = __builtin_amdgcn_mfma_f32_16x16x32_f16(fr[mb][kc], fr[nb][kc], D[mb][nb], 0, 0, 0);
      __syncthreads();
    }
    float u = 0.f;
    for (int c = 0; c < 64; ++c) u += (float)Gh[t * 80 + c];
    float z = 0.f;
    for (int i2 = 0; i2 < 64; ++i2) z += Wl[i2 * 64 + t] * __shfl(u, i2, 64);
    float nu = z * z, de = u * u;
    for (int d = 1; d < 64; d <<= 1) { nu += __shfl_xor(nu, d, 64); de += __shfl_xor(de, d, 64); }
    if (t == 0) sig[2] = sqrtf(nu / de);
  }
}

// ---------------------------------------------------------------- k_fgh
__global__ __launch_bounds__(256) void k_fgh(const float* __restrict__ x,
                                             const float* __restrict__ Wq, const float* __restrict__ bq,
                                             const float* __restrict__ Wk, const float* __restrict__ bk,
                                             const float* __restrict__ Wv, const float* __restrict__ bv,
                                             const float* __restrict__ sig,
                                             _Float16* __restrict__ K16,
                                             _Float16* __restrict__ Q16,
                                             _Float16* __restrict__ VT16,
                                             unsigned* __restrict__ maxKu) {
  __shared__ _Float16 Wsh[80 * 64];
  __shared__ float bsh[80];
  const int t = threadIdx.x;
  const float iq = LOG2E / sig[0], ik = 1.0f / sig[1], iv = 1.0f / sig[2];
  for (int idx = t; idx < 80 * 64; idx += 256) {
    const int m = idx >> 6, c = idx & 63;
    float v;
    if (m < 8)       v = Wq[m * 64 + c] * iq;
    else if (m < 16) v = Wk[(m - 8) * 64 + c] * ik;
    else             v = Wv[(m - 16) * 64 + c] * iv;
    Wsh[idx] = (_Float16)v;
  }
  if (t < 80) {
    float v;
    if (t < 8)       v = bq[t] * LOG2E;
    else if (t < 16) v = bk[t - 8];
    else             v = bv[t - 16];
    bsh[t] = v;
  }
  __syncthreads();
  const int wave = t >> 6;
  const int lane = t & 63;
  const int lane15 = lane & 15, quad = lane >> 4;
  const int tile = blockIdx.x * 4 + wave;
  const int b = tile / 576;
  const int n = (tile % 576) * 16 + lane15;
  half8 wf[5][2];
  for (int mb = 0; mb < 5; ++mb)
    for (int kc = 0; kc < 2; ++kc)
      wf[mb][kc] = *(const half8*)&Wsh[(lane15 + 16 * mb) * 64 + 32 * kc + 8 * quad];
  float4v acc[5];
  for (int mb = 0; mb < 5; ++mb) acc[mb] = *(const float4v*)&bsh[16 * mb + 4 * quad];
  const float* xb = x + (size_t)b * N_C * N_PIX;
  for (int kc = 0; kc < 2; ++kc) {
    half8 bf;
    for (int j = 0; j < 8; ++j)
      bf[j] = (_Float16)xb[(size_t)(32 * kc + 8 * quad + j) * N_PIX + n];
    for (int mb = 0; mb < 5; ++mb)
      acc[mb] = __builtin_amdgcn_mfma_f32_16x16x32_f16(wf[mb][kc], bf, acc[mb], 0, 0, 0);
  }
  {
    _Float16* dstK = K16 + ((size_t)b * N_PIX + n) * 8;
    _Float16* dstQ = Q16 + ((size_t)b * N_PIX + n) * 8;
    for (int r = 0; r < 4; ++r) {
      const int m = 4 * quad + r;
      const _Float16 v = (_Float16)acc[0][r];
      if (m < 8) dstK[m] = v; else dstQ[m - 8] = v;
    }
  }
  for (int mb = 1; mb < 5; ++mb)
    for (int r = 0; r < 4; ++r) {
      const int c = 4 * quad + r + 16 * (mb - 1);
      VT16[((size_t)b * N_C + c) * N_PIX + n] = (_Float16)acc[mb][r];
    }
  float sq = 0.f;
  if (quad < 2)
    for (int r = 0; r < 4; ++r) sq += acc[0][r] * acc[0][r];
  sq += __shfl_xor(sq, 16, 64);
  for (int d = 1; d < 64; d <<= 1) sq = fmaxf(sq, __shfl_xor(sq, d, 64));
  if (lane == 0) atomicMax(&maxKu[b], __float_as_uint(sq));
}

// ---------------------------------------------------------------- k_attn
// (R12 verbatim.) 1152 blocks: tile = b*576 + jt*2 + h; block covers keys
// [4608h, +4608), 36 rounds of 128 keys (wave w owns 32). Partial O (f32,
// undivided) + partial l to workspace. Per-wave LDS region 5120 halves:
//   [0..2047] V slot0 (64ch x 32keys, swizzled g^((c>>1)&3))
//   [2048..4095] V slot1;  [4096..4607] K slot0;  [4608..5119] K slot1.

__device__ __forceinline__ void gload16(const _Float16* g, _Float16* l) {
  __builtin_amdgcn_global_load_lds(
      (const __attribute__((address_space(1))) void*)g,
      (__attribute__((address_space(3))) void*)l, 16, 0, 0);
}
#define VMWAIT5() asm volatile("s_waitcnt vmcnt(5)" ::: "memory")

__global__ __launch_bounds__(256, 4) void k_attn(const _Float16* __restrict__ K16,
                                                 const _Float16* __restrict__ Q16,
                                                 const _Float16* __restrict__ VT16,
                                                 const unsigned* __restrict__ maxKu,
                                                 float* __restrict__ Opart,
                                                 float* __restrict__ Lpart) {
  __shared__ __align__(16) _Float16 SM[4][5120];   // 40960 B -> 4 blocks/CU
  const int wave = threadIdx.x >> 6;
  const int lane = threadIdx.x & 63;
  const int q31 = lane & 31, hi = lane >> 5;
  const int tile = blockIdx.x;            // 0..1151
  const int b = tile / 576;
  const int rm = tile % 576;
  const int jb = (rm >> 1) * 32;
  const int h = rm & 1;
  const int kh = h * (N_PIX / 2);         // this block's key range base
  const _Float16* Kb = K16 + (size_t)b * N_PIX * 8;
  const _Float16* Vb = VT16 + (size_t)b * N_C * N_PIX;
  _Float16* Rg = SM[wave];
  // staging: instr i covers channel c=16i+cl, cl=lane>>2, LDS granule kk=lane&3,
  // source granule = kk ^ ((c>>1)&3) = kk ^ ((cl>>1)&3)
  const int cl = lane >> 2, kk = lane & 3;
  const int gsw = (kk ^ ((cl >> 1) & 3)) * 8;
  // read offsets: granule g at slot g ^ ((c>>1)&3); c=q31 / 32+q31
  const int vx = (q31 >> 1) & 3;
  const int voff00 = q31 * 32 + ((hi ^ vx) << 3);
  const int voff01 = q31 * 32 + (((2 + hi) ^ vx) << 3);
  const int voff10 = 1024 + voff00;
  const int voff11 = 1024 + voff01;

  // Q B-frag: n=q31, k=8*hi+j; hi=0 lanes real (dims 0-7), hi=1 zero.
  half8 qf = {};
  if (hi == 0) qf = *(const half8*)(Q16 + ((size_t)b * N_PIX + jb + q31) * 8);
  const float maxK = sqrtf(__uint_as_float(maxKu[b]));
  float nq = 0.f;
#pragma unroll
  for (int j = 0; j < 8; ++j) nq += (float)qf[j] * (float)qf[j];
  nq += __shfl_xor(nq, 32, 64);
  const float M = sqrtf(nq) * maxK - EXP_SHIFT;
  float16v sinit;
#pragma unroll
  for (int r2 = 0; r2 < 16; ++r2) sinit[r2] = -M;

  float16v acc0 = {}, acc1 = {};
  float ls = 0.f;

#define STAGE(SLOT, I0)                                                          \
  {                                                                              \
    const int _i = (I0);                                                         \
    gload16(Kb + (size_t)(_i + q31) * 8, Rg + 4096 + (SLOT) * 512);              \
    gload16(Vb + (size_t)cl * N_PIX + _i + gsw,        Rg + (SLOT) * 2048);      \
    gload16(Vb + (size_t)(16 + cl) * N_PIX + _i + gsw, Rg + (SLOT) * 2048 + 512);\
    gload16(Vb + (size_t)(32 + cl) * N_PIX + _i + gsw, Rg + (SLOT) * 2048 + 1024);\
    gload16(Vb + (size_t)(48 + cl) * N_PIX + _i + gsw, Rg + (SLOT) * 2048 + 1536);\
  }

  STAGE(0, kh + 32 * wave)

#pragma unroll 1
  for (int r = 0; r < 36; ++r) {
    const int slot = r & 1, nslot = slot ^ 1;
    const int i1 = kh + ((r < 35) ? (128 * (r + 1) + 32 * wave) : (128 * 35 + 32 * wave));
    STAGE(nslot, i1)
    VMWAIT5();
    // K A-frag: m=key=q31, k=8*hi+j; hi=1 lanes must be ZERO (dims 8-15).
    half8 kf = *(const half8*)&Rg[4096 + slot * 512 + q31 * 8];
    if (hi) kf = (half8){};
    float16v s = __builtin_amdgcn_mfma_f32_32x32x16_f16(kf, qf, sinit, 0, 0, 0);
    int pk[8];
#pragma unroll
    for (int u = 0; u < 8; ++u) {
      const float p0 = __builtin_amdgcn_exp2f(s[2 * u]);
      const float p1 = __builtin_amdgcn_exp2f(s[2 * u + 1]);
      ls += p0 + p1;
      pk[u] = __builtin_bit_cast(int, __builtin_amdgcn_cvt_pkrtz(p0, p1));
    }
    // P C-layout -> B-layout via lane<->lane^32 exchange (R11-verified).
    const int t0 = hi ? pk[0] : pk[2];
    const int t1 = hi ? pk[1] : pk[3];
    const int t2 = hi ? pk[4] : pk[6];
    const int t3 = hi ? pk[5] : pk[7];
    const int x0 = __shfl_xor(t0, 32, 64);
    const int x1 = __shfl_xor(t1, 32, 64);
    const int x2 = __shfl_xor(t2, 32, 64);
    const int x3 = __shfl_xor(t3, 32, 64);
    int4v B0i, B1i;
    B0i[0] = hi ? x0 : pk[0];  B0i[1] = hi ? x1 : pk[1];
    B0i[2] = hi ? pk[2] : x0;  B0i[3] = hi ? pk[3] : x1;
    B1i[0] = hi ? x2 : pk[4];  B1i[1] = hi ? x3 : pk[5];
    B1i[2] = hi ? pk[6] : x2;  B1i[3] = hi ? pk[7] : x3;
    const half8 P0 = __builtin_bit_cast(half8, B0i);
    const half8 P1 = __builtin_bit_cast(half8, B1i);
    const _Float16* Vs = Rg + slot * 2048;
    const half8 v00 = *(const half8*)&Vs[voff00];
    const half8 v01 = *(const half8*)&Vs[voff01];
    const half8 v10 = *(const half8*)&Vs[voff10];
    const half8 v11 = *(const half8*)&Vs[voff11];
    acc0 = __builtin_amdgcn_mfma_f32_32x32x16_f16(v00, P0, acc0, 0, 0, 0);
    acc0 = __builtin_amdgcn_mfma_f32_32x32x16_f16(v01, P1, acc0, 0, 0, 0);
    acc1 = __builtin_amdgcn_mfma_f32_32x32x16_f16(v10, P0, acc1, 0, 0, 0);
    acc1 = __builtin_amdgcn_mfma_f32_32x32x16_f16(v11, P1, acc1, 0, 0, 0);
  }
#undef STAGE
  asm volatile("s_waitcnt vmcnt(0)" ::: "memory");  // drain dangling staging

  // ---- cross-wave merge in own region, then write partials (undivided).
  float* Ow = (float*)Rg;                // 64 x 17 f32
  float* Lw = (float*)Rg + 1100;         // 32 f32
  ls += __shfl_xor(ls, 32, 64);
  if (hi == 0) Lw[q31] = ls;
#pragma unroll
  for (int r2 = 0; r2 < 16; ++r2) Ow[lane * 17 + r2] = acc0[r2];
  __syncthreads();
  float ltot = 0.f;
#pragma unroll
  for (int w = 0; w < 4; ++w) ltot += ((const float*)SM[w])[1100 + q31];
  float* Op = Opart + (size_t)tile * 2048;
  if (wave == 0 && hi == 0) Lpart[tile * 32 + q31] = ltot;
#pragma unroll
  for (int r2 = 0; r2 < 16; ++r2) {
    float osum = 0.f;
#pragma unroll
    for (int w = 0; w < 4; ++w) osum += ((const float*)SM[w])[lane * 17 + r2];
    const int c = (r2 & 3) + 8 * (r2 >> 2) + 4 * hi;
    Op[c * 32 + q31] = osum;
  }
  __syncthreads();
#pragma unroll
  for (int r2 = 0; r2 < 16; ++r2) Ow[lane * 17 + r2] = acc1[r2];
  __syncthreads();
#pragma unroll
  for (int r2 = 0; r2 < 16; ++r2) {
    float osum = 0.f;
#pragma unroll
    for (int w = 0; w < 4; ++w) osum += ((const float*)SM[w])[lane * 17 + r2];
    const int c = 32 + (r2 & 3) + 8 * (r2 >> 2) + 4 * hi;
    Op[c * 32 + q31] = osum;
  }
}

// ---------------------------------------------------------------- k_merge
// 576 blocks (b, jt): out = gm*(O0+O1)/(l0+l1) + x.  float4 paths.
__global__ __launch_bounds__(256) void k_merge(const float* __restrict__ Opart,
                                               const float* __restrict__ Lpart,
                                               const float* __restrict__ x,
                                               const float* __restrict__ gamma,
                                               float* __restrict__ out) {
  __shared__ float Ls[32];
  const int t2 = blockIdx.x;              // 0..575
  const int b = t2 / 288, jt = t2 % 288;
  const int jb = jt * 32;
  const int tile0 = b * 576 + jt * 2;
  const float gm = gamma[0];
  const int t = threadIdx.x;
  if (t < 32) Ls[t] = Lpart[tile0 * 32 + t] + Lpart[(tile0 + 1) * 32 + t];
  __syncthreads();
  const float* O0 = Opart + (size_t)tile0 * 2048;
  const float* O1 = O0 + 2048;
  const float* xb = x + (size_t)b * N_C * N_PIX;
  float* ob = out + (size_t)b * N_C * N_PIX;
  // 2048 floats per tile-pair slice = 512 float4; 256 threads x 2.
#pragma unroll
  for (int k = 0; k < 2; ++k) {
    const int v4 = t + 256 * k;           // float4 index 0..511
    const int c = v4 >> 3, q4 = (v4 & 7) * 4;
    const size_t gi = (size_t)c * N_PIX + jb + q4;
    const float4v a = *(const float4v*)&O0[c * 32 + q4];
    const float4v bq4 = *(const float4v*)&O1[c * 32 + q4];
    const float4v xr = *(const float4v*)(xb + gi);
    float4v o;
#pragma unroll
    for (int r = 0; r < 4; ++r) o[r] = gm * (a[r] + bq4[r]) / Ls[q4 + r] + xr[r];
    *(float4v*)(ob + gi) = o;
  }
}

// ---------------------------------------------------------------- launch
extern "C" void kernel_launch(void* const* d_in, const int* in_sizes, int n_in,
                              void* d_out, int out_size, void* d_ws, size_t ws_size,
                              hipStream_t stream) {
  const float* x     = (const float*)d_in[0];
  const float* Wq    = (const float*)d_in[1];
  const float* bq    = (const float*)d_in[2];
  const float* Wk    = (const float*)d_in[3];
  const float* bk    = (const float*)d_in[4];
  const float* Wv    = (const float*)d_in[5];
  const float* bv    = (const float*)d_in[6];
  const float* gamma = (const float*)d_in[7];
  float* out = (float*)d_out;

  char* ws = (char*)d_ws;
  float*    sig   = (float*)ws;                       // 4 floats
  unsigned* maxKu = (unsigned*)(ws + 16);             // 2 uints
  _Float16* K16   = (_Float16*)(ws + 10752);          // 294912 B
  _Float16* Q16   = (_Float16*)(ws + 10752 + 294912); // 294912 B
  _Float16* VT16  = (_Float16*)(ws + 10752 + 2 * 294912); // 2359296 B
  float*    Opart = (float*)(ws + 2960384);           // 9437184 B
  float*    Lpart = (float*)(ws + 2960384 + 9437184); // 147456 B

  hipLaunchKernelGGL(k_sigma, dim3(3), dim3(64), 0, stream, Wq, Wk, Wv, sig, maxKu);
  hipLaunchKernelGGL(k_fgh, dim3(288), dim3(256), 0, stream,
                     x, Wq, bq, Wk, bk, Wv, bv, sig, K16, Q16, VT16, maxKu);
  hipLaunchKernelGGL(k_attn, dim3(1152), dim3(256), 0, stream, K16, Q16, VT16, maxKu, Opart, Lpart);
  hipLaunchKernelGGL(k_merge, dim3(576), dim3(256), 0, stream, Opart, Lpart, x, gamma, out);
}